// Round 16
// baseline (2513.348 us; speedup 1.0000x reference)
//
#include <hip/hip_runtime.h>
#include <cfloat>

// ============ INSTRUMENTATION ROUND (R13 structure + REP loops) ============
// qw x100, sims x10, agg x150 — idempotent reps (asm-laundered zero offset
// prevents hoisting) so every dispatch cracks rocprof's top-5 past the ~270us
// harness fills. Revert REPs to 1 next round.
#define REP_QW   100
#define REP_SIMS 10
#define REP_AGG  150

// Shapes (fixed by reference)
#define Bb 4
#define Tt 12
#define Nn 307
#define Wn 200        // windows: starts = 0,30,...,5970
#define ROW (Nn*64)   // 19648 floats per time-row
#define NT (Tt*Nn)    // 3684
#define KTOP 10
#define NUMEL 943104.0f  // B*64*N*T

// sims decomposition: window x sixth (a sixth = exactly 2 rows, 157KB contiguous)
#define NS 6
#define SIXTH (2*ROW)    // 39296 floats
#define SIXTH4 (SIXTH/4) // 9824 float4s

#define NG 77            // n-groups of 4 per t

// workspace layout (float offsets)
#define WS_QWL  0                      // 235776: QWl[t][n][c] (flat == window layout)
#define WS_PART (WS_QWL + Tt*ROW)      // 1200  : part[s][w]

// ---------- Kernel 1: fused prep+qw, x REP_QW ----------
__global__ __launch_bounds__(256) void qw_kernel(const float* __restrict__ x,
                                                 const float* __restrict__ Wq,
                                                 const float* __restrict__ bq,
                                                 const float* __restrict__ Wk,
                                                 float* __restrict__ ws) {
    __shared__ float wqT[64*65];   // [cp*65+o] = Wq[o*64+cp]
    __shared__ float wk[4096];
    __shared__ float xsl[256], qb[256];
    int blk = blockIdx.x;          // t*NG + g
    int t = blk / NG, g = blk % NG;
    int n0 = g * 4;
    int tid = threadIdx.x;
    int w = tid >> 6, c = tid & 63;
    int n = n0 + w;
    bool valid = (n < Nn);
    int ne = valid ? n : Nn - 1;
    size_t base = ((size_t)t * Nn + ne) * 64 + c;
    const size_t bs = (size_t)Tt * Nn * 64;

    for (int rep = 0; rep < REP_QW; ++rep) {
        int off = 0;
        asm volatile("" : "+v"(off));   // launder: no hoist/CSE across reps
        for (int i = tid; i < 4096; i += 256) {
            wqT[(i & 63)*65 + (i >> 6)] = Wq[i + off];
            wk[i] = Wk[i + off];
        }
        float xs = x[base + off] + x[base + bs + off]
                 + x[base + 2*bs + off] + x[base + 3*bs + off];
        xsl[w*64 + c] = xs;
        __syncthreads();
        float q = 4.0f * bq[c];        // this thread computes o = c
        #pragma unroll 8
        for (int cp = 0; cp < 64; ++cp) q += wqT[cp*65 + c] * xsl[w*64 + cp];
        qb[w*64 + c] = q;
        __syncthreads();
        float q2 = 0.f;
        #pragma unroll 8
        for (int o = 0; o < 64; ++o) q2 += wk[o*64 + c] * qb[w*64 + o];
        if (valid) ws[WS_QWL + (size_t)t * ROW + n*64 + c + off] = q2;
        __syncthreads();               // rep separator (benign WAR on LDS)
    }
}

// ---------- Kernel 2: sims — flat dot per (window, sixth), x REP_SIMS ----------
__global__ __launch_bounds__(256) void sims_kernel(const float* __restrict__ hist,
                                                   const float* __restrict__ ws_ro,
                                                   float* __restrict__ part) {
    int blk = blockIdx.x;            // 0..1199
    int w = blk / NS;
    int s = blk % NS;
    const float4* abase = (const float4*)(ws_ro + WS_QWL + (size_t)s * SIXTH);
    const float4* bbase = (const float4*)(hist + (size_t)(30*w) * ROW + (size_t)s * SIXTH);
    for (int rep = 0; rep < REP_SIMS; ++rep) {
        int off = 0;
        asm volatile("" : "+v"(off));
        const float4* a = abase + off;
        const float4* b = bbase + off;
        float s0 = 0.f, s1 = 0.f;
        #pragma unroll 4
        for (int i = threadIdx.x; i < SIXTH4; i += 256) {
            float4 av = a[i], bv = b[i];
            s0 += av.x*bv.x + av.y*bv.y;
            s1 += av.z*bv.z + av.w*bv.w;
        }
        float v = s0 + s1;
        #pragma unroll
        for (int o = 32; o > 0; o >>= 1) v += __shfl_down(v, o);
        __shared__ float red[4];
        int wave = threadIdx.x >> 6;
        if ((threadIdx.x & 63) == 0) red[wave] = v;
        __syncthreads();
        if (threadIdx.x == 0)
            part[s*Wn + w] = red[0] + red[1] + red[2] + red[3];
        __syncthreads();
    }
}

// ---------- Kernel 3: fused top-10 + softmax + aggregate, x REP_AGG ----------
__global__ void agg_kernel(const float* __restrict__ hist, const float* __restrict__ Wv,
                           const float* __restrict__ bvv, const float* __restrict__ ws,
                           float* __restrict__ out) {
    int blk = blockIdx.x;            // t*N + n
    int t = blk / Nn, n = blk % Nn;
    int lane = threadIdx.x;          // 64 threads, one wave
    __shared__ float aw[64];

    for (int rep = 0; rep < REP_AGG; ++rep) {
        int off = 0;
        asm volatile("" : "+v"(off));   // launder: re-load part & recompute each rep
        const float* part = ws + WS_PART + off;
        float v[4]; int ji[4];
        #pragma unroll
        for (int r = 0; r < 4; ++r) {
            int j = lane + 64*r;        // sims idx 0..198; value = sims_all[j+1]
            ji[r] = (j < Wn - 1) ? j : (1 << 29);
            if (j < Wn - 1) {
                float sm = 0.f;
                #pragma unroll
                for (int ss = 0; ss < NS; ++ss) sm += part[ss*Wn + (j + 1)];
                v[r] = sm / NUMEL;
            } else v[r] = -FLT_MAX;
        }
        float tv[KTOP]; int ti[KTOP];
        for (int k = 0; k < KTOP; ++k) {
            float bv = -FLT_MAX; int bi = 1 << 29;
            #pragma unroll
            for (int r = 0; r < 4; ++r)
                if (v[r] > bv || (v[r] == bv && ji[r] < bi)) { bv = v[r]; bi = ji[r]; }
            #pragma unroll
            for (int o = 32; o > 0; o >>= 1) {
                float ov = __shfl_xor(bv, o);
                int   oi = __shfl_xor(bi, o);
                if (ov > bv || (ov == bv && oi < bi)) { bv = ov; bi = oi; }
            }
            tv[k] = bv; ti[k] = bi;     // identical in all lanes
            #pragma unroll
            for (int r = 0; r < 4; ++r) if (ji[r] == bi) v[r] = -FLT_MAX;
        }
        float corr[KTOP];
        {
            float m = tv[0], sum = 0.f; // tv[0] is max (JAX order)
            #pragma unroll
            for (int k = 0; k < KTOP; ++k) { corr[k] = __expf(tv[k] - m); sum += corr[k]; }
            float inv = 1.0f / sum;
            #pragma unroll
            for (int k = 0; k < KTOP; ++k) corr[k] *= inv;
        }
        int c = lane;
        float a = 0.f;
        #pragma unroll
        for (int k = 0; k < KTOP; ++k) {
            int w = ti[k];              // windows[index], un-shifted (ref quirk)
            a += corr[k] * hist[(size_t)(30*w + t) * ROW + n*64 + c + off];
        }
        aw[c] = a;
        __syncthreads();
        float acc = bvv[c];
        #pragma unroll 8
        for (int cc = 0; cc < 64; ++cc) acc += Wv[c*64 + cc] * aw[cc];
        #pragma unroll
        for (int b = 0; b < Bb; ++b)
            out[(((size_t)b*Tt + t)*Nn + n)*64 + c] = acc;
        __syncthreads();                // rep separator
    }
}

extern "C" void kernel_launch(void* const* d_in, const int* in_sizes, int n_in,
                              void* d_out, int out_size, void* d_ws, size_t ws_size,
                              hipStream_t stream) {
    const float* x    = (const float*)d_in[0];
    const float* hist = (const float*)d_in[1];
    const float* Wq   = (const float*)d_in[2];
    const float* bq   = (const float*)d_in[3];
    const float* Wk   = (const float*)d_in[4];
    // d_in[5] = bk: unused — uniform shift to all sims; top-k ordering and
    // softmax are shift-invariant, so the output is unaffected.
    const float* Wv   = (const float*)d_in[6];
    const float* bv   = (const float*)d_in[7];
    float* ws  = (float*)d_ws;
    float* out = (float*)d_out;

    qw_kernel<<<Tt*NG, 256, 0, stream>>>(x, Wq, bq, Wk, ws);
    sims_kernel<<<Wn*NS, 256, 0, stream>>>(hist, ws, ws + WS_PART);
    agg_kernel<<<NT, 64, 0, stream>>>(hist, Wv, bv, ws, out);
}

// Round 17
// 59.346 us; speedup vs baseline: 42.3508x; 42.3508x over previous
//
#include <hip/hip_runtime.h>
#include <cfloat>

// Shapes (fixed by reference)
#define Bb 4
#define Tt 12
#define Nn 307
#define Wn 200        // windows: starts = 0,30,...,5970
#define ROW (Nn*64)   // 19648 floats per time-row
#define NT (Tt*Nn)    // 3684 = 4*921
#define KTOP 10
#define NUMEL 943104.0f  // B*64*N*T

// sims decomposition: window x sixth (a sixth = exactly 2 rows, 157KB contiguous)
#define NS 6
#define SIXTH (2*ROW)    // 39296 floats
#define SIXTH4 (SIXTH/4) // 9824 float4s

#define NG 77            // n-groups of 4 per t

// workspace layout (float offsets)
#define WS_QWL  0                      // 235776: QWl[t][n][c] (flat == window layout)
#define WS_PART (WS_QWL + Tt*ROW)      // 1200  : part[s][w]

// ---------- Kernel 1: fused prep+qw [measured 3.0us] ----------
__global__ __launch_bounds__(256) void qw_kernel(const float* __restrict__ x,
                                                 const float* __restrict__ Wq,
                                                 const float* __restrict__ bq,
                                                 const float* __restrict__ Wk,
                                                 float* __restrict__ ws) {
    __shared__ float wqT[64*65];   // [cp*65+o] = Wq[o*64+cp]
    __shared__ float wk[4096];
    __shared__ float xsl[256], qb[256];
    int blk = blockIdx.x;          // t*NG + g
    int t = blk / NG, g = blk % NG;
    int n0 = g * 4;
    int tid = threadIdx.x;
    for (int i = tid; i < 4096; i += 256) {
        wqT[(i & 63)*65 + (i >> 6)] = Wq[i];
        wk[i] = Wk[i];
    }
    int w = tid >> 6, c = tid & 63;
    int n = n0 + w;
    bool valid = (n < Nn);
    int ne = valid ? n : Nn - 1;
    size_t base = ((size_t)t * Nn + ne) * 64 + c;
    const size_t bs = (size_t)Tt * Nn * 64;
    float xs = x[base] + x[base + bs] + x[base + 2*bs] + x[base + 3*bs];
    xsl[w*64 + c] = xs;
    __syncthreads();
    float q = 4.0f * bq[c];        // this thread computes o = c
    #pragma unroll 8
    for (int cp = 0; cp < 64; ++cp) q += wqT[cp*65 + c] * xsl[w*64 + cp];
    qb[w*64 + c] = q;
    __syncthreads();
    float q2 = 0.f;
    #pragma unroll 8
    for (int o = 0; o < 64; ++o) q2 += wk[o*64 + c] * qb[w*64 + o];
    if (valid) ws[WS_QWL + (size_t)t * ROW + n*64 + c] = q2;
}

// ---------- Kernel 2: sims — flat dot per (window, sixth) [measured 28.4us, floor] ----------
__global__ __launch_bounds__(256) void sims_kernel(const float* __restrict__ hist,
                                                   const float* __restrict__ ws_ro,
                                                   float* __restrict__ part) {
    int blk = blockIdx.x;            // 0..1199; adjacent blocks share w (L2 locality)
    int w = blk / NS;
    int s = blk % NS;
    const float4* a = (const float4*)(ws_ro + WS_QWL + (size_t)s * SIXTH);
    const float4* b = (const float4*)(hist + (size_t)(30*w) * ROW + (size_t)s * SIXTH);
    float s0 = 0.f, s1 = 0.f;
    #pragma unroll 4
    for (int i = threadIdx.x; i < SIXTH4; i += 256) {
        float4 av = a[i], bv = b[i];
        s0 += av.x*bv.x + av.y*bv.y;
        s1 += av.z*bv.z + av.w*bv.w;
    }
    float v = s0 + s1;
    #pragma unroll
    for (int off = 32; off > 0; off >>= 1) v += __shfl_down(v, off);
    __shared__ float red[4];
    int wave = threadIdx.x >> 6;
    if ((threadIdx.x & 63) == 0) red[wave] = v;
    __syncthreads();
    if (threadIdx.x == 0)
        part[s*Wn + w] = red[0] + red[1] + red[2] + red[3];
}

// ---------- Kernel 3: agg — topk ONCE per block (wave 0), 4 (t,n) per block ----------
// R16 measured the per-wave redundant topk at ~11us (3684 waves x serial
// shuffle-select). Amortize 4x: wave 0 selects+softmaxes into LDS; all 4
// waves gather+GEMV their own (t,n). NT = 4*921 exactly (no tail).
__global__ __launch_bounds__(256) void agg_kernel(const float* __restrict__ hist,
                                                  const float* __restrict__ Wv,
                                                  const float* __restrict__ bvv,
                                                  const float* __restrict__ ws,
                                                  float* __restrict__ out) {
    int blk = blockIdx.x;            // 0..920
    int wv = threadIdx.x >> 6, lane = threadIdx.x & 63;
    __shared__ float corrL[KTOP];
    __shared__ int   tiL[KTOP];
    __shared__ float aw[256];

    if (wv == 0) {                   // ---- wave 0: top-k + softmax (once) ----
        const float* part = ws + WS_PART;
        float v[4]; int ji[4];
        #pragma unroll
        for (int r = 0; r < 4; ++r) {
            int j = lane + 64*r;     // sims idx 0..198; value = sims_all[j+1]
            ji[r] = (j < Wn - 1) ? j : (1 << 29);
            if (j < Wn - 1) {
                float sm = 0.f;
                #pragma unroll
                for (int ss = 0; ss < NS; ++ss) sm += part[ss*Wn + (j + 1)];
                v[r] = sm / NUMEL;
            } else v[r] = -FLT_MAX;
        }
        float tv[KTOP]; int ti[KTOP];
        for (int k = 0; k < KTOP; ++k) {
            float bv = -FLT_MAX; int bi = 1 << 29;
            #pragma unroll
            for (int r = 0; r < 4; ++r)
                if (v[r] > bv || (v[r] == bv && ji[r] < bi)) { bv = v[r]; bi = ji[r]; }
            #pragma unroll
            for (int off = 32; off > 0; off >>= 1) {
                float ov = __shfl_xor(bv, off);
                int   oi = __shfl_xor(bi, off);
                if (ov > bv || (ov == bv && oi < bi)) { bv = ov; bi = oi; }
            }
            tv[k] = bv; ti[k] = bi;
            #pragma unroll
            for (int r = 0; r < 4; ++r) if (ji[r] == bi) v[r] = -FLT_MAX;
        }
        if (lane < KTOP) {           // softmax via lane-parallel writes
            float m = tv[0], sum = 0.f;
            #pragma unroll
            for (int k = 0; k < KTOP; ++k) sum += __expf(tv[k] - m);
            corrL[lane] = __expf(tv[lane] - m) / sum;
            tiL[lane]   = ti[lane];
        }
    }
    __syncthreads();

    // ---- all 4 waves: gather + GEMV + broadcast for their own (t,n) ----
    int g = blk*4 + wv;              // 0..3683
    int t = g / Nn, n = g % Nn;
    int c = lane;
    float a = 0.f;
    #pragma unroll
    for (int k = 0; k < KTOP; ++k) {
        int w = tiL[k];              // windows[index], un-shifted (ref quirk)
        a += corrL[k] * hist[(size_t)(30*w + t) * ROW + n*64 + c];
    }
    aw[wv*64 + c] = a;
    __syncthreads();
    float acc = bvv[c];
    #pragma unroll 8
    for (int cc = 0; cc < 64; ++cc) acc += Wv[c*64 + cc] * aw[wv*64 + cc];
    #pragma unroll
    for (int b = 0; b < Bb; ++b)
        out[(((size_t)b*Tt + t)*Nn + n)*64 + c] = acc;
}

extern "C" void kernel_launch(void* const* d_in, const int* in_sizes, int n_in,
                              void* d_out, int out_size, void* d_ws, size_t ws_size,
                              hipStream_t stream) {
    const float* x    = (const float*)d_in[0];
    const float* hist = (const float*)d_in[1];
    const float* Wq   = (const float*)d_in[2];
    const float* bq   = (const float*)d_in[3];
    const float* Wk   = (const float*)d_in[4];
    // d_in[5] = bk: unused — uniform shift to all sims; top-k ordering and
    // softmax are shift-invariant, so the output is unaffected.
    const float* Wv   = (const float*)d_in[6];
    const float* bv   = (const float*)d_in[7];
    float* ws  = (float*)d_ws;
    float* out = (float*)d_out;

    qw_kernel<<<Tt*NG, 256, 0, stream>>>(x, Wq, bq, Wk, ws);
    sims_kernel<<<Wn*NS, 256, 0, stream>>>(hist, ws, ws + WS_PART);
    agg_kernel<<<NT/4, 256, 0, stream>>>(hist, Wv, bv, ws, out);
}

// Round 18
// 55.775 us; speedup vs baseline: 45.0623x; 1.0640x over previous
//
#include <hip/hip_runtime.h>
#include <cfloat>

// Shapes (fixed by reference)
#define Bb 4
#define Tt 12
#define Nn 307
#define Wn 200        // windows: starts = 0,30,...,5970
#define ROW (Nn*64)   // 19648 floats per time-row
#define NT (Tt*Nn)    // 3684 = 4*921
#define KTOP 10
#define NUMEL 943104.0f  // B*64*N*T

// sims decomposition: window x sixth (a sixth = exactly 2 rows, 157KB contiguous)
#define NS 6
#define SIXTH (2*ROW)    // 39296 floats
#define SIXTH4 (SIXTH/4) // 9824 float4s

#define NG 77            // n-groups of 4 per t

// workspace layout (float offsets)
#define WS_QWL  0                      // 235776: QWl[t][n][c] (flat == window layout)
#define WS_PART (WS_QWL + Tt*ROW)      // 1200  : part[s][w]

// ---------- Kernel 1: fused prep+qw [measured 3.0us] ----------
__global__ __launch_bounds__(256) void qw_kernel(const float* __restrict__ x,
                                                 const float* __restrict__ Wq,
                                                 const float* __restrict__ bq,
                                                 const float* __restrict__ Wk,
                                                 float* __restrict__ ws) {
    __shared__ float wqT[64*65];   // [cp*65+o] = Wq[o*64+cp]
    __shared__ float wk[4096];
    __shared__ float xsl[256], qb[256];
    int blk = blockIdx.x;          // t*NG + g
    int t = blk / NG, g = blk % NG;
    int n0 = g * 4;
    int tid = threadIdx.x;
    for (int i = tid; i < 4096; i += 256) {
        wqT[(i & 63)*65 + (i >> 6)] = Wq[i];
        wk[i] = Wk[i];
    }
    int w = tid >> 6, c = tid & 63;
    int n = n0 + w;
    bool valid = (n < Nn);
    int ne = valid ? n : Nn - 1;
    size_t base = ((size_t)t * Nn + ne) * 64 + c;
    const size_t bs = (size_t)Tt * Nn * 64;
    float xs = x[base] + x[base + bs] + x[base + 2*bs] + x[base + 3*bs];
    xsl[w*64 + c] = xs;
    __syncthreads();
    float q = 4.0f * bq[c];        // this thread computes o = c
    #pragma unroll 8
    for (int cp = 0; cp < 64; ++cp) q += wqT[cp*65 + c] * xsl[w*64 + cp];
    qb[w*64 + c] = q;
    __syncthreads();
    float q2 = 0.f;
    #pragma unroll 8
    for (int o = 0; o < 64; ++o) q2 += wk[o*64 + c] * qb[w*64 + o];
    if (valid) ws[WS_QWL + (size_t)t * ROW + n*64 + c] = q2;
}

// ---------- Kernel 2: sims — flat dot per (window, sixth) [measured 28.4us, floor] ----------
__global__ __launch_bounds__(256) void sims_kernel(const float* __restrict__ hist,
                                                   const float* __restrict__ ws_ro,
                                                   float* __restrict__ part) {
    int blk = blockIdx.x;            // 0..1199; adjacent blocks share w (L2 locality)
    int w = blk / NS;
    int s = blk % NS;
    const float4* a = (const float4*)(ws_ro + WS_QWL + (size_t)s * SIXTH);
    const float4* b = (const float4*)(hist + (size_t)(30*w) * ROW + (size_t)s * SIXTH);
    float s0 = 0.f, s1 = 0.f;
    #pragma unroll 4
    for (int i = threadIdx.x; i < SIXTH4; i += 256) {
        float4 av = a[i], bv = b[i];
        s0 += av.x*bv.x + av.y*bv.y;
        s1 += av.z*bv.z + av.w*bv.w;
    }
    float v = s0 + s1;
    #pragma unroll
    for (int off = 32; off > 0; off >>= 1) v += __shfl_down(v, off);
    __shared__ float red[4];
    int wave = threadIdx.x >> 6;
    if ((threadIdx.x & 63) == 0) red[wave] = v;
    __syncthreads();
    if (threadIdx.x == 0)
        part[s*Wn + w] = red[0] + red[1] + red[2] + red[3];
}

// ---------- Kernel 3: agg — topk once/block + LDS-staged Wv GEMV ----------
// The GEMV read Wv[c*64+cc] (c=lane) was 64 cache lines per wave-load = 4096
// L1 line-transactions per block x 3684 -> prime suspect for agg's 12.7us
// (R16 REP). Fix: stage Wv in LDS with +1 pad; (o*65+cc)%32 = (o+cc)%32 ->
// conflict-free reads, zero global transactions. Same summation order ->
// bitwise-identical output.
__global__ __launch_bounds__(256) void agg_kernel(const float* __restrict__ hist,
                                                  const float* __restrict__ Wv,
                                                  const float* __restrict__ bvv,
                                                  const float* __restrict__ ws,
                                                  float* __restrict__ out) {
    int blk = blockIdx.x;            // 0..920
    int wv = threadIdx.x >> 6, lane = threadIdx.x & 63;
    __shared__ float WvL[64*65];     // [o*65+cc] = Wv[o*64+cc], padded
    __shared__ float corrL[KTOP];
    __shared__ int   tiL[KTOP];
    __shared__ float aw[256];

    for (int i = threadIdx.x; i < 4096; i += 256)
        WvL[(i >> 6)*65 + (i & 63)] = Wv[i];   // coalesced read, bank-sequential write

    if (wv == 0) {                   // ---- wave 0: top-k + softmax (once) ----
        const float* part = ws + WS_PART;
        float v[4]; int ji[4];
        #pragma unroll
        for (int r = 0; r < 4; ++r) {
            int j = lane + 64*r;     // sims idx 0..198; value = sims_all[j+1]
            ji[r] = (j < Wn - 1) ? j : (1 << 29);
            if (j < Wn - 1) {
                float sm = 0.f;
                #pragma unroll
                for (int ss = 0; ss < NS; ++ss) sm += part[ss*Wn + (j + 1)];
                v[r] = sm / NUMEL;
            } else v[r] = -FLT_MAX;
        }
        float tv[KTOP]; int ti[KTOP];
        for (int k = 0; k < KTOP; ++k) {
            float bv = -FLT_MAX; int bi = 1 << 29;
            #pragma unroll
            for (int r = 0; r < 4; ++r)
                if (v[r] > bv || (v[r] == bv && ji[r] < bi)) { bv = v[r]; bi = ji[r]; }
            #pragma unroll
            for (int off = 32; off > 0; off >>= 1) {
                float ov = __shfl_xor(bv, off);
                int   oi = __shfl_xor(bi, off);
                if (ov > bv || (ov == bv && oi < bi)) { bv = ov; bi = oi; }
            }
            tv[k] = bv; ti[k] = bi;
            #pragma unroll
            for (int r = 0; r < 4; ++r) if (ji[r] == bi) v[r] = -FLT_MAX;
        }
        if (lane < KTOP) {           // softmax via lane-parallel writes
            float m = tv[0], sum = 0.f;
            #pragma unroll
            for (int k = 0; k < KTOP; ++k) sum += __expf(tv[k] - m);
            corrL[lane] = __expf(tv[lane] - m) / sum;
            tiL[lane]   = ti[lane];
        }
    }
    __syncthreads();

    // ---- all 4 waves: gather + GEMV + broadcast for their own (t,n) ----
    int g = blk*4 + wv;              // 0..3683
    int t = g / Nn, n = g % Nn;
    int c = lane;
    float a = 0.f;
    #pragma unroll
    for (int k = 0; k < KTOP; ++k) {
        int w = tiL[k];              // windows[index], un-shifted (ref quirk)
        a += corrL[k] * hist[(size_t)(30*w + t) * ROW + n*64 + c];
    }
    aw[wv*64 + c] = a;
    __syncthreads();
    float acc = bvv[c];
    #pragma unroll 8
    for (int cc = 0; cc < 64; ++cc) acc += WvL[c*65 + cc] * aw[wv*64 + cc];
    #pragma unroll
    for (int b = 0; b < Bb; ++b)
        out[(((size_t)b*Tt + t)*Nn + n)*64 + c] = acc;
}

extern "C" void kernel_launch(void* const* d_in, const int* in_sizes, int n_in,
                              void* d_out, int out_size, void* d_ws, size_t ws_size,
                              hipStream_t stream) {
    const float* x    = (const float*)d_in[0];
    const float* hist = (const float*)d_in[1];
    const float* Wq   = (const float*)d_in[2];
    const float* bq   = (const float*)d_in[3];
    const float* Wk   = (const float*)d_in[4];
    // d_in[5] = bk: unused — uniform shift to all sims; top-k ordering and
    // softmax are shift-invariant, so the output is unaffected.
    const float* Wv   = (const float*)d_in[6];
    const float* bv   = (const float*)d_in[7];
    float* ws  = (float*)d_ws;
    float* out = (float*)d_out;

    qw_kernel<<<Tt*NG, 256, 0, stream>>>(x, Wq, bq, Wk, ws);
    sims_kernel<<<Wn*NS, 256, 0, stream>>>(hist, ws, ws + WS_PART);
    agg_kernel<<<NT/4, 256, 0, stream>>>(hist, Wv, bv, ws, out);
}

// Round 19
// 54.789 us; speedup vs baseline: 45.8734x; 1.0180x over previous
//
#include <hip/hip_runtime.h>
#include <cfloat>

// Shapes (fixed by reference)
#define Bb 4
#define Tt 12
#define Nn 307
#define Wn 200        // windows: starts = 0,30,...,5970
#define ROW (Nn*64)   // 19648 floats per time-row
#define NT (Tt*Nn)    // 3684 = 4*921
#define KTOP 10
#define NUMEL 943104.0f  // B*64*N*T

// sims decomposition: window x sixth (a sixth = exactly 2 rows, 157KB contiguous)
#define NS 6
#define SIXTH (2*ROW)    // 39296 floats
#define SIXTH4 (SIXTH/4) // 9824 float4s

#define NG 77            // n-groups of 4 per t
#define NWT 921          // wave-tasks in agg (4 cells each)
#define NAB 231          // agg blocks (4 wave-tasks each; last block 1 active)

// workspace layout (float offsets)
#define WS_QWL  0                      // 235776: QWl[t][n][c] (flat == window layout)
#define WS_PART (WS_QWL + Tt*ROW)      // 1200  : part[s][w]

// ---------- Kernel 1: fused prep+qw [measured 3.0us] ----------
__global__ __launch_bounds__(256) void qw_kernel(const float* __restrict__ x,
                                                 const float* __restrict__ Wq,
                                                 const float* __restrict__ bq,
                                                 const float* __restrict__ Wk,
                                                 float* __restrict__ ws) {
    __shared__ float wqT[64*65];   // [cp*65+o] = Wq[o*64+cp]
    __shared__ float wk[4096];
    __shared__ float xsl[256], qb[256];
    int blk = blockIdx.x;          // t*NG + g
    int t = blk / NG, g = blk % NG;
    int n0 = g * 4;
    int tid = threadIdx.x;
    for (int i = tid; i < 4096; i += 256) {
        wqT[(i & 63)*65 + (i >> 6)] = Wq[i];
        wk[i] = Wk[i];
    }
    int w = tid >> 6, c = tid & 63;
    int n = n0 + w;
    bool valid = (n < Nn);
    int ne = valid ? n : Nn - 1;
    size_t base = ((size_t)t * Nn + ne) * 64 + c;
    const size_t bs = (size_t)Tt * Nn * 64;
    float xs = x[base] + x[base + bs] + x[base + 2*bs] + x[base + 3*bs];
    xsl[w*64 + c] = xs;
    __syncthreads();
    float q = 4.0f * bq[c];        // this thread computes o = c
    #pragma unroll 8
    for (int cp = 0; cp < 64; ++cp) q += wqT[cp*65 + c] * xsl[w*64 + cp];
    qb[w*64 + c] = q;
    __syncthreads();
    float q2 = 0.f;
    #pragma unroll 8
    for (int o = 0; o < 64; ++o) q2 += wk[o*64 + c] * qb[w*64 + o];
    if (valid) ws[WS_QWL + (size_t)t * ROW + n*64 + c] = q2;
}

// ---------- Kernel 2: sims — flat dot per (window, sixth) [measured 28.4us, floor] ----------
__global__ __launch_bounds__(256) void sims_kernel(const float* __restrict__ hist,
                                                   const float* __restrict__ ws_ro,
                                                   float* __restrict__ part) {
    int blk = blockIdx.x;            // 0..1199; adjacent blocks share w (L2 locality)
    int w = blk / NS;
    int s = blk % NS;
    const float4* a = (const float4*)(ws_ro + WS_QWL + (size_t)s * SIXTH);
    const float4* b = (const float4*)(hist + (size_t)(30*w) * ROW + (size_t)s * SIXTH);
    float s0 = 0.f, s1 = 0.f;
    #pragma unroll 4
    for (int i = threadIdx.x; i < SIXTH4; i += 256) {
        float4 av = a[i], bv = b[i];
        s0 += av.x*bv.x + av.y*bv.y;
        s1 += av.z*bv.z + av.w*bv.w;
    }
    float v = s0 + s1;
    #pragma unroll
    for (int off = 32; off > 0; off >>= 1) v += __shfl_down(v, off);
    __shared__ float red[4];
    int wave = threadIdx.x >> 6;
    if ((threadIdx.x & 63) == 0) red[wave] = v;
    __syncthreads();
    if (threadIdx.x == 0)
        part[s*Wn + w] = red[0] + red[1] + red[2] + red[3];
}

// ---------- Kernel 3: agg — 4 cells/wave, all-float4 gather & store ----------
// R18 left gather/store at 256B per wave-instruction (scalar per lane). Now
// lane l covers cell l/16, channels (l%16)*4..+3: every hist read and out
// write is a per-lane float4 (1KB/wave-instr, 4x fewer instructions; 4x
// fewer waves at 4x width = Little's-law neutral). GEMV keeps cc=0..63
// order -> bitwise-identical. aw stride 68 -> q-groups in distinct banks.
__global__ __launch_bounds__(256) void agg_kernel(const float* __restrict__ hist,
                                                  const float* __restrict__ Wv,
                                                  const float* __restrict__ bvv,
                                                  const float* __restrict__ ws,
                                                  float* __restrict__ out) {
    int blk = blockIdx.x;            // 0..230
    int wv = threadIdx.x >> 6, lane = threadIdx.x & 63;
    __shared__ float WvL[64*65];     // [o*65+cc], padded
    __shared__ float corrL[KTOP];
    __shared__ int   tiL[KTOP];
    __shared__ float aw[4][4][68];   // [wave][cell q][cc], stride-68: banks cc+4q

    for (int i = threadIdx.x; i < 4096; i += 256)
        WvL[(i >> 6)*65 + (i & 63)] = Wv[i];

    if (wv == 0) {                   // ---- wave 0: top-k + softmax (once per block) ----
        const float* part = ws + WS_PART;
        float v[4]; int ji[4];
        #pragma unroll
        for (int r = 0; r < 4; ++r) {
            int j = lane + 64*r;     // sims idx 0..198; value = sims_all[j+1]
            ji[r] = (j < Wn - 1) ? j : (1 << 29);
            if (j < Wn - 1) {
                float sm = 0.f;
                #pragma unroll
                for (int ss = 0; ss < NS; ++ss) sm += part[ss*Wn + (j + 1)];
                v[r] = sm / NUMEL;
            } else v[r] = -FLT_MAX;
        }
        float tv[KTOP]; int ti[KTOP];
        for (int k = 0; k < KTOP; ++k) {
            float bv = -FLT_MAX; int bi = 1 << 29;
            #pragma unroll
            for (int r = 0; r < 4; ++r)
                if (v[r] > bv || (v[r] == bv && ji[r] < bi)) { bv = v[r]; bi = ji[r]; }
            #pragma unroll
            for (int off = 32; off > 0; off >>= 1) {
                float ov = __shfl_xor(bv, off);
                int   oi = __shfl_xor(bi, off);
                if (ov > bv || (ov == bv && oi < bi)) { bv = ov; bi = oi; }
            }
            tv[k] = bv; ti[k] = bi;
            #pragma unroll
            for (int r = 0; r < 4; ++r) if (ji[r] == bi) v[r] = -FLT_MAX;
        }
        if (lane < KTOP) {           // softmax via lane-parallel writes
            float m = tv[0], sum = 0.f;
            #pragma unroll
            for (int k = 0; k < KTOP; ++k) sum += __expf(tv[k] - m);
            corrL[lane] = __expf(tv[lane] - m) / sum;
            tiL[lane]   = ti[lane];
        }
    }
    __syncthreads();

    int j = blk*4 + wv;              // wave-task 0..923
    bool act = (j < NWT);
    int q   = lane >> 4;             // cell within task
    int g   = j*4 + q;               // flat (t,n) index
    int t   = g / Nn, n = g % Nn;    // per-lane (handles t-straddle naturally)
    int ch0 = (lane & 15) * 4;

    if (act) {
        float4 a4 = make_float4(0.f, 0.f, 0.f, 0.f);
        #pragma unroll
        for (int k = 0; k < KTOP; ++k) {
            int w = tiL[k];          // windows[index], un-shifted (ref quirk)
            float4 hv = *(const float4*)(hist + (size_t)(30*w + t) * ROW + n*64 + ch0);
            float ck = corrL[k];
            a4.x += ck*hv.x; a4.y += ck*hv.y; a4.z += ck*hv.z; a4.w += ck*hv.w;
        }
        *(float4*)(&aw[wv][q][ch0]) = a4;
    }
    __syncthreads();
    if (act) {
        float4 b4 = *(const float4*)(bvv + ch0);
        float4 acc = b4;
        const float* awq = aw[wv][q];
        #pragma unroll 8
        for (int cc = 0; cc < 64; ++cc) {   // same order as reference GEMV
            float av = awq[cc];
            acc.x += WvL[(ch0+0)*65 + cc] * av;
            acc.y += WvL[(ch0+1)*65 + cc] * av;
            acc.z += WvL[(ch0+2)*65 + cc] * av;
            acc.w += WvL[(ch0+3)*65 + cc] * av;
        }
        #pragma unroll
        for (int b = 0; b < Bb; ++b)
            *(float4*)(out + (((size_t)b*Tt + t)*Nn + n)*64 + ch0) = acc;
    }
}

extern "C" void kernel_launch(void* const* d_in, const int* in_sizes, int n_in,
                              void* d_out, int out_size, void* d_ws, size_t ws_size,
                              hipStream_t stream) {
    const float* x    = (const float*)d_in[0];
    const float* hist = (const float*)d_in[1];
    const float* Wq   = (const float*)d_in[2];
    const float* bq   = (const float*)d_in[3];
    const float* Wk   = (const float*)d_in[4];
    // d_in[5] = bk: unused — uniform shift to all sims; top-k ordering and
    // softmax are shift-invariant, so the output is unaffected.
    const float* Wv   = (const float*)d_in[6];
    const float* bv   = (const float*)d_in[7];
    float* ws  = (float*)d_ws;
    float* out = (float*)d_out;

    qw_kernel<<<Tt*NG, 256, 0, stream>>>(x, Wq, bq, Wk, ws);
    sims_kernel<<<Wn*NS, 256, 0, stream>>>(hist, ws, ws + WS_PART);
    agg_kernel<<<NAB, 256, 0, stream>>>(hist, Wv, bv, ws, out);
}